// Round 19
// baseline (439.175 us; speedup 1.0000x reference)
//
#include <hip/hip_runtime.h>
#include <cstdint>
#include <cstddef>

typedef __bf16 bf16;
typedef __bf16 bf16x8 __attribute__((ext_vector_type(8)));
typedef __bf16 bf16x4 __attribute__((ext_vector_type(4)));
typedef float f32x4 __attribute__((ext_vector_type(4)));
typedef unsigned int uint;

#define D_MODEL 2048
#define NH 16
#define HD 128
#define LQ 2048
#define LT 4096

__device__ __forceinline__ void gload16(const void* g, void* l) {
  __builtin_amdgcn_global_load_lds((const __attribute__((address_space(1))) void*)g,
                                   (__attribute__((address_space(3))) void*)l, 16, 0, 0);
}

// ---------------- fused preprocessing: x->bf16, 4x W->bf16, past K/V copies ----------------
// block segments: [0,8192) x | [8192,24576) W4 | [24576,32768) pk | [32768,40960) pv
__global__ __launch_bounds__(256) void prep(const float* __restrict__ x,
                                            const float* __restrict__ Wq, const float* __restrict__ Wk,
                                            const float* __restrict__ Wv, const float* __restrict__ Wo,
                                            const float* __restrict__ pk, const float* __restrict__ pv,
                                            bf16* __restrict__ xb, bf16* __restrict__ wb,
                                            float* __restrict__ kout, bf16* __restrict__ kbf,
                                            float* __restrict__ vout) {
  const int bid = blockIdx.x;
  if (bid < 8192) {                       // x -> xb
    int i = (bid * 256 + threadIdx.x) * 4;
    float4 v = *(const float4*)(x + i);
    bf16x4 o = { (bf16)v.x, (bf16)v.y, (bf16)v.z, (bf16)v.w };
    *(bf16x4*)(xb + i) = o;
  } else if (bid < 24576) {               // weights -> wb (4 slices)
    const int r = bid - 8192;
    const int z = r >> 12;
    const float* s = (z == 0) ? Wq : (z == 1) ? Wk : (z == 2) ? Wv : Wo;
    int i = ((r & 4095) * 256 + threadIdx.x) * 4;
    float4 v = *(const float4*)(s + i);
    bf16x4 o = { (bf16)v.x, (bf16)v.y, (bf16)v.z, (bf16)v.w };
    *(bf16x4*)(wb + (size_t)z * 4194304 + i) = o;
  } else if (bid < 32768) {               // past K -> kout fp32 + kbf bf16
    int i = ((bid - 24576) * 256 + threadIdx.x) * 4;
    int bh = i >> 18;
    int rem = i & 262143;
    size_t o = ((size_t)bh << 19) + rem;
    float4 v = *(const float4*)(pk + i);
    *(float4*)(kout + o) = v;
    bf16x4 ob = { (bf16)v.x, (bf16)v.y, (bf16)v.z, (bf16)v.w };
    *(bf16x4*)(kbf + o) = ob;
  } else {                                // past V -> vout fp32
    int i = ((bid - 32768) * 256 + threadIdx.x) * 4;
    int bh = i >> 18;
    int rem = i & 262143;
    size_t o = ((size_t)bh << 19) + rem;
    float4 v = *(const float4*)(pv + i);
    *(float4*)(vout + o) = v;
  }
}

// ---------------- QKV projection (R13): 128x128 tile, BK=64, dbuf, counted vmcnt(8) ----------------
__global__ __launch_bounds__(256, 2) void qkv_gemm128(const bf16* __restrict__ xb, const bf16* __restrict__ wb,
    const float* __restrict__ bq, const float* __restrict__ bk, const float* __restrict__ bv,
    bf16* __restrict__ qb, float* __restrict__ kout, float* __restrict__ vout, bf16* __restrict__ kbf) {
  __shared__ alignas(16) bf16 sA[2][128 * 64];   // 16 KB per buf
  __shared__ alignas(16) bf16 sB[2][128 * 64];
  const int tid = threadIdx.x, lane = tid & 63, w = tid >> 6;
  const int fr = lane & 15, fg = lane >> 4;
  const int wm = (w >> 1) * 64, wn = (w & 1) * 64;
  // T1 XCD-chunked swizzle (nwg=1536, cpx=192)
  const int flat = blockIdx.x;
  const int swz = (flat & 7) * 192 + (flat >> 3);
  const int z = swz >> 9;                        // 512 blocks per z
  const int idx = swz & 511;
  const int n0 = (idx & 15) * 128;
  const int m0 = (idx >> 4) * 128;               // 32 M-tiles (M = B*L = 4096)
  const bf16* A = xb;
  const bf16* Bw = wb + (size_t)z * 4194304;
  f32x4 acc[4][4];
#pragma unroll
  for (int a = 0; a < 4; a++)
#pragma unroll
    for (int b = 0; b < 4; b++) acc[a][b] = (f32x4){0.f, 0.f, 0.f, 0.f};

  // 128 rows x 8 granules = 1024 chunks; 4 chunks/thread; src granule = (c&7)^(row&7)
#define STG(k0s, buf) do {                                                                   \
    _Pragma("unroll")                                                                        \
    for (int j = 0; j < 4; j++) {                                                            \
      const int c_ = j * 256 + tid;                                                          \
      const int rS = c_ >> 3;                                                                \
      const int gS = (c_ & 7) ^ (rS & 7);                                                    \
      gload16(A  + (size_t)(m0 + rS) * 2048 + (k0s) + gS * 8,                                \
              &sA[buf][(j * 256 + (tid & 192)) * 8]);                                        \
      gload16(Bw + (size_t)(n0 + rS) * 2048 + (k0s) + gS * 8,                                \
              &sB[buf][(j * 256 + (tid & 192)) * 8]);                                        \
    }                                                                                        \
  } while (0)

  STG(0, 0);
  STG(64, 1);
  for (int t = 0; t < 32; ++t) {
    const int bsel = t & 1;
    asm volatile("s_waitcnt vmcnt(8)\n\ts_barrier" ::: "memory");
    bf16x8 af[2][4], bfr[2][4];
#pragma unroll
    for (int kk = 0; kk < 2; kk++) {
#pragma unroll
      for (int ni = 0; ni < 4; ni++) {
        const int row = wn + ni * 16 + fr;
        bfr[kk][ni] = *(const bf16x8*)(&sB[bsel][row * 64 + (((kk * 4 + fg) ^ (row & 7)) * 8)]);
      }
#pragma unroll
      for (int mi = 0; mi < 4; mi++) {
        const int row = wm + mi * 16 + fr;
        af[kk][mi] = *(const bf16x8*)(&sA[bsel][row * 64 + (((kk * 4 + fg) ^ (row & 7)) * 8)]);
      }
    }
    asm volatile("s_waitcnt lgkmcnt(0)\n\ts_barrier" ::: "memory");
    const int ks = ((t + 2) * 64) & 2047;          // wrap at end: harmless re-stage
    STG(ks, bsel);
    __builtin_amdgcn_s_setprio(1);
#pragma unroll
    for (int kk = 0; kk < 2; kk++)
#pragma unroll
      for (int mi = 0; mi < 4; mi++)
#pragma unroll
        for (int ni = 0; ni < 4; ni++)
          acc[mi][ni] = __builtin_amdgcn_mfma_f32_16x16x32_bf16(af[kk][mi], bfr[kk][ni], acc[mi][ni], 0, 0, 0);
    __builtin_amdgcn_s_setprio(0);
  }
#undef STG
  asm volatile("s_waitcnt vmcnt(0)" ::: "memory");
  const float* bias = (z == 0) ? bq : (z == 1 ? bk : bv);
#pragma unroll
  for (int ni = 0; ni < 4; ni++) {
    const int col = n0 + wn + ni * 16 + fr;
    const float bi = bias[col];
#pragma unroll
    for (int mi = 0; mi < 4; mi++) {
#pragma unroll
      for (int r = 0; r < 4; r++) {
        const int row = m0 + wm + mi * 16 + fg * 4 + r;
        float v = acc[mi][ni][r] + bi;
        if (z == 0) {
          // fold 1/sqrt(128) * log2(e) so attn can use v_exp_f32 (exp2) directly
          qb[(size_t)row * 2048 + col] = (bf16)(v * 0.12751744955867606f);
        } else {
          size_t co = (((size_t)(row >> 11) * 16 + (col >> 7)) * 4096 + 2048 + (row & 2047)) * 128 + (col & 127);
          if (z == 1) { kout[co] = v; kbf[co] = (bf16)v; }
          else        { vout[co] = v; }
        }
      }
    }
  }
}

// ---------------- V cache -> transposed bf16  [BH][128][4096] ----------------
__global__ __launch_bounds__(256) void build_vt(const float* __restrict__ vsrc, bf16* __restrict__ vtb) {
  __shared__ float tile[64][65];
  const int tid = threadIdx.x;
  const int bh = blockIdx.z;
  const int t0 = blockIdx.x * 64, d0 = blockIdx.y * 64;
  const float* src = vsrc + ((size_t)bh * LT + t0) * HD + d0;
#pragma unroll
  for (int i = 0; i < 4; i++) {
    int idx = i * 256 + tid;
    int rr = idx >> 4, c4 = (idx & 15) * 4;
    float4 v = *(const float4*)(src + rr * HD + c4);
    tile[rr][c4 + 0] = v.x; tile[rr][c4 + 1] = v.y; tile[rr][c4 + 2] = v.z; tile[rr][c4 + 3] = v.w;
  }
  __syncthreads();
  bf16* dst = vtb + (size_t)bh * HD * LT + (size_t)d0 * LT + t0;
#pragma unroll
  for (int i = 0; i < 4; i++) {
    int idx = i * 256 + tid;
    int dr = idx >> 4, c4 = (idx & 15) * 4;
    bf16x4 o = { (bf16)tile[c4 + 0][dr], (bf16)tile[c4 + 1][dr],
                 (bf16)tile[c4 + 2][dr], (bf16)tile[c4 + 3][dr] };
    *(bf16x4*)(dst + (size_t)dr * LT + c4) = o;
  }
}

// ---------------- flash attention (R18): 8 waves x 64 q-rows, KEY-SPLIT halves ----------------
// R16's reuse (4 q-sets share each kf/vf) WITHOUT its TLP loss: 512-thread
// blocks, waves 0-3 handle keys 0-31, waves 4-7 keys 32-63 -> per-wave LDS
// reads halve (8KB K-half + 8KB V-half). Grid 256 = 1 block/CU x 8 waves =
// 2 waves/SIMD (same TLP as R15) with HALF the per-CU LDS traffic. Partial
// ctx/sum combined once at the end via padded-stride LDS reduce.
__global__ __launch_bounds__(512, 2) void attn(const bf16* __restrict__ qb, const bf16* __restrict__ kb,
                                               const bf16* __restrict__ vtb, bf16* __restrict__ ctxb) {
  __shared__ alignas(16) bf16 kbuf[2][64 * 128];    // [key][d], swizzled (32 KB)
  __shared__ alignas(16) bf16 vtbuf[2][128 * 64];   // [d][key], swizzled (32 KB)
  const int tid = threadIdx.x, lane = tid & 63, w = tid >> 6;   // w in 0..7
  const int fr = lane & 15, fg = lane >> 4;
  const int half = w >> 2;                          // 0: keys 0-31, 1: keys 32-63
  const int g = w & 3;                              // q-group within tile
  // bh-grouped swizzle: 256 blocks; XCD i&7 handles heads {4*(i&7) .. 4*(i&7)+3}
  const int i_ = blockIdx.x + 8 * blockIdx.y;    // 0..255
  const int j_ = i_ >> 3;                        // 0..31
  const int bh = (i_ & 7) * 4 + (j_ & 3);
  const int q0 = (j_ >> 2) * 256;                // 8 q-tiles of 256
  const int b = bh >> 4;
  // four 16-row q-sets per wave: q = q0 + g*64 + s*16 + fr (col index after swap)
  bf16x8 aq[4][4];
#pragma unroll
  for (int s = 0; s < 4; s++) {
    const bf16* qrow = qb + (size_t)(b * LQ + q0 + g * 64 + s * 16 + fr) * D_MODEL + (bh & 15) * HD;
#pragma unroll
    for (int c = 0; c < 4; c++) aq[s][c] = *(const bf16x8*)(qrow + c * 32 + fg * 8);
  }
  const bf16* Kb = kb + (size_t)bh * LT * HD;
  const bf16* Vt = vtb + (size_t)bh * HD * LT;
  f32x4 ctx[4][8], sum_[4];          // partial (this wave's key-half)
#pragma unroll
  for (int s = 0; s < 4; s++) {
#pragma unroll
    for (int d = 0; d < 8; d++) ctx[s][d] = (f32x4){0.f, 0.f, 0.f, 0.f};
    sum_[s] = (f32x4){0.f, 0.f, 0.f, 0.f};
  }
  bf16x8 vones;
#pragma unroll
  for (int j = 0; j < 8; j++) vones[j] = (bf16)1.0f;

  // staging: 512 threads, 2 rounds each. K: rows j*32 + w*4 + (lane>>4);
  // V: rows j*64 + w*8 + (lane>>3). Inverse-swizzled source, linear dest.
#define STAGE_K(k0s, sel)                                                                    \
  do {                                                                                       \
    _Pragma("unroll")                                                                        \
    for (int j = 0; j < 2; j++) {                                                            \
      const int krow = j * 32 + w * 4 + (lane >> 4);                                         \
      const int kscol = ((lane & 15) ^ (krow & 7)) * 8;                                      \
      gload16(Kb + (size_t)((k0s) + krow) * HD + kscol, &kbuf[sel][(j * 32 + w * 4) * HD]);  \
    }                                                                                        \
  } while (0)
#define STAGE_V(k0s, sel)                                                                    \
  do {                                                                                       \
    _Pragma("unroll")                                                                        \
    for (int j = 0; j < 2; j++) {                                                            \
      const int vrw = j * 64 + w * 8 + (lane >> 3);                                          \
      const int vscol = ((lane & 7) ^ (vrw & 7)) * 8;                                        \
      gload16(Vt + (size_t)vrw * LT + (k0s) + vscol, &vtbuf[sel][(j * 64 + w * 8) * 64]);    \
    }                                                                                        \
  } while (0)

  STAGE_K(0, 0);
  STAGE_V(0, 0);
  int sel = 0;
  for (int k0 = 0; k0 < LT; k0 += 64) {
    __syncthreads();                       // buf[sel] staged; prev reads of buf[sel^1] done
    const int kn = (k0 + 64) & (LT - 1);   // wrap on last iter (harmless re-stage)
    STAGE_K(kn, sel ^ 1);                  // K first: consumed first next iter
    const bf16* kcur = &kbuf[sel][0];
    const bf16* vcur = &vtbuf[sel][0];
    // S^T = K Q^T over this wave's key-half: local nn=0,1 -> key rows (half*2+nn)*16+..
    f32x4 sS[4][2];
    __builtin_amdgcn_s_setprio(1);
#pragma unroll
    for (int nn = 0; nn < 2; nn++) {
      const int n = half * 2 + nn;
#pragma unroll
      for (int s = 0; s < 4; s++) sS[s][nn] = (f32x4){0.f, 0.f, 0.f, 0.f};
#pragma unroll
      for (int c = 0; c < 4; c++) {
        bf16x8 kf = *(const bf16x8*)(kcur + (n * 16 + fr) * HD + (((c * 4 + fg) ^ (fr & 7)) * 8));
#pragma unroll
        for (int s = 0; s < 4; s++)
          sS[s][nn] = __builtin_amdgcn_mfma_f32_16x16x32_bf16(kf, aq[s][c], sS[s][nn], 0, 0, 0);
      }
    }
    __builtin_amdgcn_s_setprio(0);
    STAGE_V(kn, sel ^ 1);                  // V later: not consumed until next iter's PV
    // P = exp2(S): pack pairs along r, permlane-redistribute -> ONE A-frag per wave
    bf16x8 pf[4];
#pragma unroll
    for (int s = 0; s < 4; s++) {
      uint Dd[2][2];
#pragma unroll
      for (int nn = 0; nn < 2; nn++) {
        uint hb[4];
#pragma unroll
        for (int r = 0; r < 4; r++) {
          bf16 h = (bf16)__builtin_amdgcn_exp2f(sS[s][nn][r]);
          unsigned short us;
          __builtin_memcpy(&us, &h, 2);
          hb[r] = us;
        }
        Dd[nn][0] = hb[0] | (hb[1] << 16);
        Dd[nn][1] = hb[2] | (hb[3] << 16);
      }
      uint T[4];
#pragma unroll
      for (int p = 0; p < 2; p++) {
        uint a = Dd[0][p], b2 = Dd[1][p];
        asm("v_permlane32_swap_b32 %0, %1" : "+v"(a), "+v"(b2));
        asm("v_permlane16_swap_b32 %0, %1" : "+v"(a), "+v"(b2));
        T[p] = a; T[2 + p] = b2;
      }
      union { uint u[4]; bf16x8 v; } cv;
      cv.u[0] = T[0]; cv.u[1] = T[1]; cv.u[2] = T[2]; cv.u[3] = T[3];
      pf[s] = cv.v;
    }
    // PV over this wave's key-half: vf granule block (half*4+fg)
    __builtin_amdgcn_s_setprio(1);
#pragma unroll
    for (int d = 0; d < 8; d++) {
      bf16x8 vf = *(const bf16x8*)(vcur + (d * 16 + fr) * 64 + (((half * 4 + fg) ^ (fr & 7)) * 8));
#pragma unroll
      for (int s = 0; s < 4; s++)
        ctx[s][d] = __builtin_amdgcn_mfma_f32_16x16x32_bf16(pf[s], vf, ctx[s][d], 0, 0, 0);
    }
#pragma unroll
    for (int s = 0; s < 4; s++)
      sum_[s] = __builtin_amdgcn_mfma_f32_16x16x32_bf16(pf[s], vones, sum_[s], 0, 0, 0);
    __builtin_amdgcn_s_setprio(0);
    sel ^= 1;
  }
#undef STAGE_K
#undef STAGE_V
  // combine key-halves: hi waves deposit partials in LDS, lo waves add.
  // Drain wrap-stage loads first (they write into these buffers).
  asm volatile("s_waitcnt vmcnt(0)" ::: "memory");
  __syncthreads();
  {
    float* redc = (float*)&kbuf[0][0];            // 4 waves x 64 lanes x 36 f32 = 36 KB
    float* reds = redc + 4 * 64 * 36;             // + 4 KB sums
#pragma unroll
    for (int s = 0; s < 4; s++) {
      if (half == 1) {
        float* dst = redc + (g * 64 + lane) * 36;
#pragma unroll
        for (int d = 0; d < 8; d++) *(f32x4*)(dst + d * 4) = ctx[s][d];
        *(f32x4*)(reds + (g * 64 + lane) * 4) = sum_[s];
      }
      __syncthreads();
      if (half == 0) {
        const float* src = redc + (g * 64 + lane) * 36;
#pragma unroll
        for (int d = 0; d < 8; d++) {
          f32x4 t = *(const f32x4*)(src + d * 4);
          ctx[s][d] += t;
        }
        f32x4 ts = *(const f32x4*)(reds + (g * 64 + lane) * 4);
        sum_[s] += ts;
      }
      __syncthreads();
    }
  }
  if (half == 0) {
#pragma unroll
    for (int s = 0; s < 4; s++) {
      float inv[4];
#pragma unroll
      for (int r = 0; r < 4; r++) inv[r] = 1.f / sum_[s][r];
      bf16* crow = ctxb + (size_t)(b * LQ + q0 + g * 64 + s * 16 + fg * 4) * D_MODEL + (bh & 15) * HD + fr;
#pragma unroll
      for (int r = 0; r < 4; r++)
#pragma unroll
        for (int d = 0; d < 8; d++)
          crow[(size_t)r * D_MODEL + d * 16] = (bf16)(ctx[s][d][r] * inv[r]);
    }
  }
}

// ---------------- output projection (R11 ordering): counted-vmcnt dbuf at 128^2, BK=64 ----------------
__global__ __launch_bounds__(256, 2) void out_gemm(const bf16* __restrict__ cb, const bf16* __restrict__ wo,
                                                   const float* __restrict__ bo, float* __restrict__ out) {
  __shared__ alignas(16) bf16 sA[2][128 * 64];   // 16 KB per buf
  __shared__ alignas(16) bf16 sB[2][128 * 64];
  const int tid = threadIdx.x, lane = tid & 63, w = tid >> 6;
  const int fr = lane & 15, fg = lane >> 4;
  const int wm = (w >> 1) * 64, wn = (w & 1) * 64;
  // T1: bijective XCD-chunked swizzle (nwg=512, cpx=64)
  const int flat = blockIdx.x;
  const int swz = (flat & 7) * 64 + (flat >> 3);
  const int n0 = (swz & 15) * 128;
  const int m0 = (swz >> 4) * 128;
  const bf16* A = cb;
  const bf16* Bw = wo;
  f32x4 acc[4][4];
#pragma unroll
  for (int a = 0; a < 4; a++)
#pragma unroll
    for (int b = 0; b < 4; b++) acc[a][b] = (f32x4){0.f, 0.f, 0.f, 0.f};

  // 128 rows x 8 granules = 1024 chunks; 4 chunks/thread; src granule = (c&7)^(row&7)
#define STG(k0s, buf) do {                                                                   \
    _Pragma("unroll")                                                                        \
    for (int j = 0; j < 4; j++) {                                                            \
      const int c_ = j * 256 + tid;                                                          \
      const int rS = c_ >> 3;                                                                \
      const int gS = (c_ & 7) ^ (rS & 7);                                                    \
      gload16(A  + (size_t)(m0 + rS) * 2048 + (k0s) + gS * 8,                                \
              &sA[buf][(j * 256 + (tid & 192)) * 8]);                                        \
      gload16(Bw + (size_t)(n0 + rS) * 2048 + (k0s) + gS * 8,                                \
              &sB[buf][(j * 256 + (tid & 192)) * 8]);                                        \
    }                                                                                        \
  } while (0)

  STG(0, 0);
  STG(64, 1);
  for (int t = 0; t < 32; ++t) {
    const int bsel = t & 1;
    asm volatile("s_waitcnt vmcnt(8)\n\ts_barrier" ::: "memory");
    bf16x8 af[2][4], bfr[2][4];
#pragma unroll
    for (int kk = 0; kk < 2; kk++) {
#pragma unroll
      for (int ni = 0; ni < 4; ni++) {
        const int row = wn + ni * 16 + fr;
        bfr[kk][ni] = *(const bf16x8*)(&sB[bsel][row * 64 + (((kk * 4 + fg) ^ (row & 7)) * 8)]);
      }
#pragma unroll
      for (int mi = 0; mi < 4; mi++) {
        const int row = wm + mi * 16 + fr;
        af[kk][mi] = *(const bf16x8*)(&sA[bsel][row * 64 + (((kk * 4 + fg) ^ (row & 7)) * 8)]);
      }
    }
    asm volatile("s_waitcnt lgkmcnt(0)\n\ts_barrier" ::: "memory");
    const int ks = ((t + 2) * 64) & 2047;          // wrap at end: harmless re-stage
    STG(ks, bsel);
    __builtin_amdgcn_s_setprio(1);
#pragma unroll
    for (int kk = 0; kk < 2; kk++)
#pragma unroll
      for (int mi = 0; mi < 4; mi++)
#pragma unroll
        for (int ni = 0; ni < 4; ni++)
          acc[mi][ni] = __builtin_amdgcn_mfma_f32_16x16x32_bf16(af[kk][mi], bfr[kk][ni], acc[mi][ni], 0, 0, 0);
    __builtin_amdgcn_s_setprio(0);
  }
#undef STG
  asm volatile("s_waitcnt vmcnt(0)" ::: "memory");
#pragma unroll
  for (int ni = 0; ni < 4; ni++) {
    int col = n0 + wn + ni * 16 + fr;
    float bi = bo[col];
#pragma unroll
    for (int mi = 0; mi < 4; mi++)
#pragma unroll
      for (int r = 0; r < 4; r++) {
        int row = m0 + wm + mi * 16 + fg * 4 + r;
        out[(size_t)row * 2048 + col] = acc[mi][ni][r] + bi;
      }
  }
}

extern "C" void kernel_launch(void* const* d_in, const int* in_sizes, int n_in,
                              void* d_out, int out_size, void* d_ws, size_t ws_size,
                              hipStream_t stream) {
  const float* x  = (const float*)d_in[0];
  const float* pk = (const float*)d_in[1];
  const float* pv = (const float*)d_in[2];
  const float* Wq = (const float*)d_in[3];
  const float* bq = (const float*)d_in[4];
  const float* Wk = (const float*)d_in[5];
  const float* bk = (const float*)d_in[6];
  const float* Wv = (const float*)d_in[7];
  const float* bv = (const float*)d_in[8];
  const float* Wo = (const float*)d_in[9];
  const float* bo = (const float*)d_in[10];

  float* out  = (float*)d_out;
  float* kout = out + 8388608;   // B*L*D
  float* vout = out + 25165824;

  char* p = (char*)d_ws;
  bf16* xb  = (bf16*)p;                   // 16 MiB, reused as ctxb after QKV gemm
  bf16* wb  = (bf16*)(p + 16777216);      // 32 MiB: Wq,Wk,Wv,Wo bf16
  bf16* qb  = (bf16*)(p + 50331648);      // 16 MiB (pre-scaled Q)
  bf16* kbf = (bf16*)(p + 67108864);      // 32 MiB K cache bf16 [BH][4096][128]
  bf16* vtb = (bf16*)(p + 100663296);     // 32 MiB V^T cache bf16 [BH][128][4096]
  bf16* ctxb = xb;

  prep<<<40960, 256, 0, stream>>>(x, Wq, Wk, Wv, Wo, pk, pv, xb, wb, kout, kbf, vout);
  qkv_gemm128<<<1536, 256, 0, stream>>>(xb, wb, bq, bk, bv, qb, kout, vout, kbf);
  build_vt<<<dim3(64, 2, 32), 256, 0, stream>>>(vout, vtb);
  attn<<<dim3(8, 32), 512, 0, stream>>>(qb, kbf, vtb, ctxb);
  out_gemm<<<512, 256, 0, stream>>>(ctxb, wb + 12582912, bo, out);
}

// Round 20
// 359.982 us; speedup vs baseline: 1.2200x; 1.2200x over previous
//
#include <hip/hip_runtime.h>
#include <cstdint>
#include <cstddef>

typedef __bf16 bf16;
typedef __bf16 bf16x8 __attribute__((ext_vector_type(8)));
typedef __bf16 bf16x4 __attribute__((ext_vector_type(4)));
typedef float f32x4 __attribute__((ext_vector_type(4)));
typedef unsigned int uint;

#define D_MODEL 2048
#define NH 16
#define HD 128
#define LQ 2048
#define LT 4096

__device__ __forceinline__ void gload16(const void* g, void* l) {
  __builtin_amdgcn_global_load_lds((const __attribute__((address_space(1))) void*)g,
                                   (__attribute__((address_space(3))) void*)l, 16, 0, 0);
}

// ---------------- fused preprocessing: x->bf16, 4x W->bf16, past K/V copies ----------------
// block segments: [0,8192) x | [8192,24576) W4 | [24576,32768) pk | [32768,40960) pv
__global__ __launch_bounds__(256) void prep(const float* __restrict__ x,
                                            const float* __restrict__ Wq, const float* __restrict__ Wk,
                                            const float* __restrict__ Wv, const float* __restrict__ Wo,
                                            const float* __restrict__ pk, const float* __restrict__ pv,
                                            bf16* __restrict__ xb, bf16* __restrict__ wb,
                                            float* __restrict__ kout, bf16* __restrict__ kbf,
                                            float* __restrict__ vout) {
  const int bid = blockIdx.x;
  if (bid < 8192) {                       // x -> xb
    int i = (bid * 256 + threadIdx.x) * 4;
    float4 v = *(const float4*)(x + i);
    bf16x4 o = { (bf16)v.x, (bf16)v.y, (bf16)v.z, (bf16)v.w };
    *(bf16x4*)(xb + i) = o;
  } else if (bid < 24576) {               // weights -> wb (4 slices)
    const int r = bid - 8192;
    const int z = r >> 12;
    const float* s = (z == 0) ? Wq : (z == 1) ? Wk : (z == 2) ? Wv : Wo;
    int i = ((r & 4095) * 256 + threadIdx.x) * 4;
    float4 v = *(const float4*)(s + i);
    bf16x4 o = { (bf16)v.x, (bf16)v.y, (bf16)v.z, (bf16)v.w };
    *(bf16x4*)(wb + (size_t)z * 4194304 + i) = o;
  } else if (bid < 32768) {               // past K -> kout fp32 + kbf bf16
    int i = ((bid - 24576) * 256 + threadIdx.x) * 4;
    int bh = i >> 18;
    int rem = i & 262143;
    size_t o = ((size_t)bh << 19) + rem;
    float4 v = *(const float4*)(pk + i);
    *(float4*)(kout + o) = v;
    bf16x4 ob = { (bf16)v.x, (bf16)v.y, (bf16)v.z, (bf16)v.w };
    *(bf16x4*)(kbf + o) = ob;
  } else {                                // past V -> vout fp32
    int i = ((bid - 32768) * 256 + threadIdx.x) * 4;
    int bh = i >> 18;
    int rem = i & 262143;
    size_t o = ((size_t)bh << 19) + rem;
    float4 v = *(const float4*)(pv + i);
    *(float4*)(vout + o) = v;
  }
}

// ---------------- QKV projection (R13): 128x128 tile, BK=64, dbuf, counted vmcnt(8),
// R11 ordering (reads -> lgkmcnt(0)+barrier -> stage t+2 -> MFMAs). Grid 1536 =
// exactly 3 residency rounds of 512 (2 blocks/CU).
__global__ __launch_bounds__(256, 2) void qkv_gemm128(const bf16* __restrict__ xb, const bf16* __restrict__ wb,
    const float* __restrict__ bq, const float* __restrict__ bk, const float* __restrict__ bv,
    bf16* __restrict__ qb, float* __restrict__ kout, float* __restrict__ vout, bf16* __restrict__ kbf) {
  __shared__ alignas(16) bf16 sA[2][128 * 64];   // 16 KB per buf
  __shared__ alignas(16) bf16 sB[2][128 * 64];
  const int tid = threadIdx.x, lane = tid & 63, w = tid >> 6;
  const int fr = lane & 15, fg = lane >> 4;
  const int wm = (w >> 1) * 64, wn = (w & 1) * 64;
  // T1 XCD-chunked swizzle (nwg=1536, cpx=192)
  const int flat = blockIdx.x;
  const int swz = (flat & 7) * 192 + (flat >> 3);
  const int z = swz >> 9;                        // 512 blocks per z
  const int idx = swz & 511;
  const int n0 = (idx & 15) * 128;
  const int m0 = (idx >> 4) * 128;               // 32 M-tiles (M = B*L = 4096)
  const bf16* A = xb;
  const bf16* Bw = wb + (size_t)z * 4194304;
  f32x4 acc[4][4];
#pragma unroll
  for (int a = 0; a < 4; a++)
#pragma unroll
    for (int b = 0; b < 4; b++) acc[a][b] = (f32x4){0.f, 0.f, 0.f, 0.f};

  // 128 rows x 8 granules = 1024 chunks; 4 chunks/thread; src granule = (c&7)^(row&7)
#define STG(k0s, buf) do {                                                                   \
    _Pragma("unroll")                                                                        \
    for (int j = 0; j < 4; j++) {                                                            \
      const int c_ = j * 256 + tid;                                                          \
      const int rS = c_ >> 3;                                                                \
      const int gS = (c_ & 7) ^ (rS & 7);                                                    \
      gload16(A  + (size_t)(m0 + rS) * 2048 + (k0s) + gS * 8,                                \
              &sA[buf][(j * 256 + (tid & 192)) * 8]);                                        \
      gload16(Bw + (size_t)(n0 + rS) * 2048 + (k0s) + gS * 8,                                \
              &sB[buf][(j * 256 + (tid & 192)) * 8]);                                        \
    }                                                                                        \
  } while (0)

  STG(0, 0);
  STG(64, 1);
  for (int t = 0; t < 32; ++t) {
    const int bsel = t & 1;
    asm volatile("s_waitcnt vmcnt(8)\n\ts_barrier" ::: "memory");
    bf16x8 af[2][4], bfr[2][4];
#pragma unroll
    for (int kk = 0; kk < 2; kk++) {
#pragma unroll
      for (int ni = 0; ni < 4; ni++) {
        const int row = wn + ni * 16 + fr;
        bfr[kk][ni] = *(const bf16x8*)(&sB[bsel][row * 64 + (((kk * 4 + fg) ^ (row & 7)) * 8)]);
      }
#pragma unroll
      for (int mi = 0; mi < 4; mi++) {
        const int row = wm + mi * 16 + fr;
        af[kk][mi] = *(const bf16x8*)(&sA[bsel][row * 64 + (((kk * 4 + fg) ^ (row & 7)) * 8)]);
      }
    }
    asm volatile("s_waitcnt lgkmcnt(0)\n\ts_barrier" ::: "memory");
    const int ks = ((t + 2) * 64) & 2047;          // wrap at end: harmless re-stage
    STG(ks, bsel);
    __builtin_amdgcn_s_setprio(1);
#pragma unroll
    for (int kk = 0; kk < 2; kk++)
#pragma unroll
      for (int mi = 0; mi < 4; mi++)
#pragma unroll
        for (int ni = 0; ni < 4; ni++)
          acc[mi][ni] = __builtin_amdgcn_mfma_f32_16x16x32_bf16(af[kk][mi], bfr[kk][ni], acc[mi][ni], 0, 0, 0);
    __builtin_amdgcn_s_setprio(0);
  }
#undef STG
  asm volatile("s_waitcnt vmcnt(0)" ::: "memory");
  const float* bias = (z == 0) ? bq : (z == 1 ? bk : bv);
#pragma unroll
  for (int ni = 0; ni < 4; ni++) {
    const int col = n0 + wn + ni * 16 + fr;
    const float bi = bias[col];
#pragma unroll
    for (int mi = 0; mi < 4; mi++) {
#pragma unroll
      for (int r = 0; r < 4; r++) {
        const int row = m0 + wm + mi * 16 + fg * 4 + r;
        float v = acc[mi][ni][r] + bi;
        if (z == 0) {
          // fold 1/sqrt(128) * log2(e) so attn can use v_exp_f32 (exp2) directly
          qb[(size_t)row * 2048 + col] = (bf16)(v * 0.12751744955867606f);
        } else {
          size_t co = (((size_t)(row >> 11) * 16 + (col >> 7)) * 4096 + 2048 + (row & 2047)) * 128 + (col & 127);
          if (z == 1) { kout[co] = v; kbf[co] = (bf16)v; }
          else        { vout[co] = v; }
        }
      }
    }
  }
}

// ---------------- V cache -> transposed bf16  [BH][128][4096] ----------------
__global__ __launch_bounds__(256) void build_vt(const float* __restrict__ vsrc, bf16* __restrict__ vtb) {
  __shared__ float tile[64][65];
  const int tid = threadIdx.x;
  const int bh = blockIdx.z;
  const int t0 = blockIdx.x * 64, d0 = blockIdx.y * 64;
  const float* src = vsrc + ((size_t)bh * LT + t0) * HD + d0;
#pragma unroll
  for (int i = 0; i < 4; i++) {
    int idx = i * 256 + tid;
    int rr = idx >> 4, c4 = (idx & 15) * 4;
    float4 v = *(const float4*)(src + rr * HD + c4);
    tile[rr][c4 + 0] = v.x; tile[rr][c4 + 1] = v.y; tile[rr][c4 + 2] = v.z; tile[rr][c4 + 3] = v.w;
  }
  __syncthreads();
  bf16* dst = vtb + (size_t)bh * HD * LT + (size_t)d0 * LT + t0;
#pragma unroll
  for (int i = 0; i < 4; i++) {
    int idx = i * 256 + tid;
    int dr = idx >> 4, c4 = (idx & 15) * 4;
    bf16x4 o = { (bf16)tile[c4 + 0][dr], (bf16)tile[c4 + 1][dr],
                 (bf16)tile[c4 + 2][dr], (bf16)tile[c4 + 3][dr] };
    *(bf16x4*)(dst + (size_t)dr * LT + c4) = o;
  }
}

// ---------------- flash attention: 4 waves x 32 q-rows, KVBLK=64 (R15 structure) ----------------
// R17 final: 32 q/wave at 2 blocks/CU (2 waves/SIMD) is the reuse-vs-TLP balance
// point (R16: 64q/1-block = latency-exposed; R18: key-split single barrier domain
// = staging exposed). K(t+1) staged right after barrier, V(t+1) after QK^T.
__global__ __launch_bounds__(256, 2) void attn(const bf16* __restrict__ qb, const bf16* __restrict__ kb,
                                               const bf16* __restrict__ vtb, bf16* __restrict__ ctxb) {
  __shared__ alignas(16) bf16 kbuf[2][64 * 128];    // [key][d], swizzled
  __shared__ alignas(16) bf16 vtbuf[2][128 * 64];   // [d][key], swizzled
  const int tid = threadIdx.x, lane = tid & 63, w = tid >> 6;   // w in 0..3
  const int fr = lane & 15, fg = lane >> 4;
  // bh-grouped swizzle: linear id i -> XCD i&7 handles heads {4*(i&7) .. 4*(i&7)+3}
  const int i_ = blockIdx.x + 16 * blockIdx.y;   // 0..511
  const int j_ = i_ >> 3;
  const int bh = (i_ & 7) * 4 + (j_ & 3);
  const int q0 = (j_ >> 2) * 128;
  const int b = bh >> 4;
  // two 16-row q-sets per wave: q = q0 + w*32 + s*16 + fr (col index after swap)
  bf16x8 aq[2][4];
#pragma unroll
  for (int s = 0; s < 2; s++) {
    const bf16* qrow = qb + (size_t)(b * LQ + q0 + w * 32 + s * 16 + fr) * D_MODEL + (bh & 15) * HD;
#pragma unroll
    for (int c = 0; c < 4; c++) aq[s][c] = *(const bf16x8*)(qrow + c * 32 + fg * 8);
  }
  const bf16* Kb = kb + (size_t)bh * LT * HD;
  const bf16* Vt = vtb + (size_t)bh * HD * LT;
  f32x4 ctx[2][8], sum_[2];          // ctx/sum in ROW layout (q = fg*4+r)
#pragma unroll
  for (int s = 0; s < 2; s++) {
#pragma unroll
    for (int d = 0; d < 8; d++) ctx[s][d] = (f32x4){0.f, 0.f, 0.f, 0.f};
    sum_[s] = (f32x4){0.f, 0.f, 0.f, 0.f};
  }
  bf16x8 vones;
#pragma unroll
  for (int j = 0; j < 8; j++) vones[j] = (bf16)1.0f;

#define STAGE_K(k0s, sel)                                                                    \
  do {                                                                                       \
    _Pragma("unroll")                                                                        \
    for (int j = 0; j < 4; j++) {                                                            \
      const int krow = j * 16 + w * 4 + (lane >> 4);                                         \
      const int kscol = ((lane & 15) ^ (krow & 7)) * 8;                                      \
      gload16(Kb + (size_t)((k0s) + krow) * HD + kscol, &kbuf[sel][(j * 16 + w * 4) * HD]);  \
    }                                                                                        \
  } while (0)
#define STAGE_V(k0s, sel)                                                                    \
  do {                                                                                       \
    _Pragma("unroll")                                                                        \
    for (int j = 0; j < 4; j++) {                                                            \
      const int vrw = j * 32 + w * 8 + (lane >> 3);                                          \
      const int vscol = ((lane & 7) ^ (vrw & 7)) * 8;                                        \
      gload16(Vt + (size_t)vrw * LT + (k0s) + vscol, &vtbuf[sel][(j * 32 + w * 8) * 64]);    \
    }                                                                                        \
  } while (0)

  STAGE_K(0, 0);
  STAGE_V(0, 0);
  int sel = 0;
  for (int k0 = 0; k0 < LT; k0 += 64) {
    __syncthreads();                       // buf[sel] staged; prev reads of buf[sel^1] done
    const int kn = (k0 + 64) & (LT - 1);   // wrap on last iter (harmless re-stage)
    STAGE_K(kn, sel ^ 1);                  // K first: consumed first next iter
    const bf16* kcur = &kbuf[sel][0];
    const bf16* vcur = &vtbuf[sel][0];
    // S^T = K Q^T: sS[s][n][r] = S[key = n*16 + fg*4 + r][q = set s, col fr]
    f32x4 sS[2][4];
    __builtin_amdgcn_s_setprio(1);
#pragma unroll
    for (int n = 0; n < 4; n++) {
      sS[0][n] = (f32x4){0.f, 0.f, 0.f, 0.f};
      sS[1][n] = (f32x4){0.f, 0.f, 0.f, 0.f};
#pragma unroll
      for (int c = 0; c < 4; c++) {
        bf16x8 kf = *(const bf16x8*)(kcur + (n * 16 + fr) * HD + (((c * 4 + fg) ^ (fr & 7)) * 8));
        sS[0][n] = __builtin_amdgcn_mfma_f32_16x16x32_bf16(kf, aq[0][c], sS[0][n], 0, 0, 0);
        sS[1][n] = __builtin_amdgcn_mfma_f32_16x16x32_bf16(kf, aq[1][c], sS[1][n], 0, 0, 0);
      }
    }
    __builtin_amdgcn_s_setprio(0);
    STAGE_V(kn, sel ^ 1);                  // V later: not consumed until next iter's PV
    // P = exp2(S): pack bf16 pairs along r, permlane-redistribute to A-frags
    bf16x8 pf[2][2];
#pragma unroll
    for (int s = 0; s < 2; s++) {
      uint Dd[4][2];
#pragma unroll
      for (int n = 0; n < 4; n++) {
        uint hb[4];
#pragma unroll
        for (int r = 0; r < 4; r++) {
          bf16 h = (bf16)__builtin_amdgcn_exp2f(sS[s][n][r]);
          unsigned short us;
          __builtin_memcpy(&us, &h, 2);
          hb[r] = us;
        }
        Dd[n][0] = hb[0] | (hb[1] << 16);
        Dd[n][1] = hb[2] | (hb[3] << 16);
      }
#pragma unroll
      for (int c = 0; c < 2; c++) {
        uint T[4];
#pragma unroll
        for (int p = 0; p < 2; p++) {
          uint a = Dd[2 * c][p], b2 = Dd[2 * c + 1][p];
          asm("v_permlane32_swap_b32 %0, %1" : "+v"(a), "+v"(b2));
          asm("v_permlane16_swap_b32 %0, %1" : "+v"(a), "+v"(b2));
          T[p] = a; T[2 + p] = b2;
        }
        union { uint u[4]; bf16x8 v; } cv;
        cv.u[0] = T[0]; cv.u[1] = T[1]; cv.u[2] = T[2]; cv.u[3] = T[3];
        pf[s][c] = cv.v;
      }
    }
    // PV: ctx[q-row][d] += P * V (V fragments read inline from LDS)
    __builtin_amdgcn_s_setprio(1);
#pragma unroll
    for (int d = 0; d < 8; d++) {
      bf16x8 v0 = *(const bf16x8*)(vcur + (d * 16 + fr) * 64 + ((fg ^ (fr & 7)) * 8));
      ctx[0][d] = __builtin_amdgcn_mfma_f32_16x16x32_bf16(pf[0][0], v0, ctx[0][d], 0, 0, 0);
      ctx[1][d] = __builtin_amdgcn_mfma_f32_16x16x32_bf16(pf[1][0], v0, ctx[1][d], 0, 0, 0);
      bf16x8 v1 = *(const bf16x8*)(vcur + (d * 16 + fr) * 64 + (((4 + fg) ^ (fr & 7)) * 8));
      ctx[0][d] = __builtin_amdgcn_mfma_f32_16x16x32_bf16(pf[0][1], v1, ctx[0][d], 0, 0, 0);
      ctx[1][d] = __builtin_amdgcn_mfma_f32_16x16x32_bf16(pf[1][1], v1, ctx[1][d], 0, 0, 0);
    }
    // denominator via MFMA against all-ones B (rows = q -> matches ctx layout)
#pragma unroll
    for (int s = 0; s < 2; s++) {
      sum_[s] = __builtin_amdgcn_mfma_f32_16x16x32_bf16(pf[s][0], vones, sum_[s], 0, 0, 0);
      sum_[s] = __builtin_amdgcn_mfma_f32_16x16x32_bf16(pf[s][1], vones, sum_[s], 0, 0, 0);
    }
    __builtin_amdgcn_s_setprio(0);
    sel ^= 1;
  }
#undef STAGE_K
#undef STAGE_V
#pragma unroll
  for (int s = 0; s < 2; s++) {
    float inv[4];
#pragma unroll
    for (int r = 0; r < 4; r++) inv[r] = 1.f / sum_[s][r];
    bf16* crow = ctxb + (size_t)(b * LQ + q0 + w * 32 + s * 16 + fg * 4) * D_MODEL + (bh & 15) * HD + fr;
#pragma unroll
    for (int r = 0; r < 4; r++)
#pragma unroll
      for (int d = 0; d < 8; d++)
        crow[(size_t)r * D_MODEL + d * 16] = (bf16)(ctx[s][d][r] * inv[r]);
  }
}

// ---------------- output projection (R11 ordering): counted-vmcnt dbuf at 128^2, BK=64 ----------------
__global__ __launch_bounds__(256, 2) void out_gemm(const bf16* __restrict__ cb, const bf16* __restrict__ wo,
                                                   const float* __restrict__ bo, float* __restrict__ out) {
  __shared__ alignas(16) bf16 sA[2][128 * 64];   // 16 KB per buf
  __shared__ alignas(16) bf16 sB[2][128 * 64];
  const int tid = threadIdx.x, lane = tid & 63, w = tid >> 6;
  const int fr = lane & 15, fg = lane >> 4;
  const int wm = (w >> 1) * 64, wn = (w & 1) * 64;
  // T1: bijective XCD-chunked swizzle (nwg=512, cpx=64)
  const int flat = blockIdx.x;
  const int swz = (flat & 7) * 64 + (flat >> 3);
  const int n0 = (swz & 15) * 128;
  const int m0 = (swz >> 4) * 128;
  const bf16* A = cb;
  const bf16* Bw = wo;
  f32x4 acc[4][4];
#pragma unroll
  for (int a = 0; a < 4; a++)
#pragma unroll
    for (int b = 0; b < 4; b++) acc[a][b] = (f32x4){0.f, 0.f, 0.f, 0.f};

  // 128 rows x 8 granules = 1024 chunks; 4 chunks/thread; src granule = (c&7)^(row&7)
#define STG(k0s, buf) do {                                                                   \
    _Pragma("unroll")                                                                        \
    for (int j = 0; j < 4; j++) {                                                            \
      const int c_ = j * 256 + tid;                                                          \
      const int rS = c_ >> 3;                                                                \
      const int gS = (c_ & 7) ^ (rS & 7);                                                    \
      gload16(A  + (size_t)(m0 + rS) * 2048 + (k0s) + gS * 8,                                \
              &sA[buf][(j * 256 + (tid & 192)) * 8]);                                        \
      gload16(Bw + (size_t)(n0 + rS) * 2048 + (k0s) + gS * 8,                                \
              &sB[buf][(j * 256 + (tid & 192)) * 8]);                                        \
    }                                                                                        \
  } while (0)

  STG(0, 0);
  STG(64, 1);
  for (int t = 0; t < 32; ++t) {
    const int bsel = t & 1;
    asm volatile("s_waitcnt vmcnt(8)\n\ts_barrier" ::: "memory");
    bf16x8 af[2][4], bfr[2][4];
#pragma unroll
    for (int kk = 0; kk < 2; kk++) {
#pragma unroll
      for (int ni = 0; ni < 4; ni++) {
        const int row = wn + ni * 16 + fr;
        bfr[kk][ni] = *(const bf16x8*)(&sB[bsel][row * 64 + (((kk * 4 + fg) ^ (row & 7)) * 8)]);
      }
#pragma unroll
      for (int mi = 0; mi < 4; mi++) {
        const int row = wm + mi * 16 + fr;
        af[kk][mi] = *(const bf16x8*)(&sA[bsel][row * 64 + (((kk * 4 + fg) ^ (row & 7)) * 8)]);
      }
    }
    asm volatile("s_waitcnt lgkmcnt(0)\n\ts_barrier" ::: "memory");
    const int ks = ((t + 2) * 64) & 2047;          // wrap at end: harmless re-stage
    STG(ks, bsel);
    __builtin_amdgcn_s_setprio(1);
#pragma unroll
    for (int kk = 0; kk < 2; kk++)
#pragma unroll
      for (int mi = 0; mi < 4; mi++)
#pragma unroll
        for (int ni = 0; ni < 4; ni++)
          acc[mi][ni] = __builtin_amdgcn_mfma_f32_16x16x32_bf16(af[kk][mi], bfr[kk][ni], acc[mi][ni], 0, 0, 0);
    __builtin_amdgcn_s_setprio(0);
  }
#undef STG
  asm volatile("s_waitcnt vmcnt(0)" ::: "memory");
#pragma unroll
  for (int ni = 0; ni < 4; ni++) {
    int col = n0 + wn + ni * 16 + fr;
    float bi = bo[col];
#pragma unroll
    for (int mi = 0; mi < 4; mi++)
#pragma unroll
      for (int r = 0; r < 4; r++) {
        int row = m0 + wm + mi * 16 + fg * 4 + r;
        out[(size_t)row * 2048 + col] = acc[mi][ni][r] + bi;
      }
  }
}

extern "C" void kernel_launch(void* const* d_in, const int* in_sizes, int n_in,
                              void* d_out, int out_size, void* d_ws, size_t ws_size,
                              hipStream_t stream) {
  const float* x  = (const float*)d_in[0];
  const float* pk = (const float*)d_in[1];
  const float* pv = (const float*)d_in[2];
  const float* Wq = (const float*)d_in[3];
  const float* bq = (const float*)d_in[4];
  const float* Wk = (const float*)d_in[5];
  const float* bk = (const float*)d_in[6];
  const float* Wv = (const float*)d_in[7];
  const float* bv = (const float*)d_in[8];
  const float* Wo = (const float*)d_in[9];
  const float* bo = (const float*)d_in[10];

  float* out  = (float*)d_out;
  float* kout = out + 8388608;   // B*L*D
  float* vout = out + 25165824;

  char* p = (char*)d_ws;
  bf16* xb  = (bf16*)p;                   // 16 MiB, reused as ctxb after QKV gemm
  bf16* wb  = (bf16*)(p + 16777216);      // 32 MiB: Wq,Wk,Wv,Wo bf16
  bf16* qb  = (bf16*)(p + 50331648);      // 16 MiB (pre-scaled Q)
  bf16* kbf = (bf16*)(p + 67108864);      // 32 MiB K cache bf16 [BH][4096][128]
  bf16* vtb = (bf16*)(p + 100663296);     // 32 MiB V^T cache bf16 [BH][128][4096]
  bf16* ctxb = xb;

  prep<<<40960, 256, 0, stream>>>(x, Wq, Wk, Wv, Wo, pk, pv, xb, wb, kout, kbf, vout);
  qkv_gemm128<<<1536, 256, 0, stream>>>(xb, wb, bq, bk, bv, qb, kout, vout, kbf);
  build_vt<<<dim3(64, 2, 32), 256, 0, stream>>>(vout, vtb);
  attn<<<dim3(16, 32), 256, 0, stream>>>(qb, kbf, vtb, ctxb);
  out_gemm<<<512, 256, 0, stream>>>(ctxb, wb + 12582912, bo, out);
}